// Round 2
// baseline (438.199 us; speedup 1.0000x reference)
//
#include <hip/hip_runtime.h>
#include <hip/hip_bf16.h>

typedef unsigned short ushort_t;
typedef __attribute__((ext_vector_type(8))) short short8;
typedef __attribute__((ext_vector_type(4))) float f32x4;

#define M_DIM 8192
#define N_DIM 8192
#define K_DIM 2048
#define BM 128
#define BN 128
#define BK 64

__device__ __forceinline__ ushort_t f2bf(float f) {
    union { float f; unsigned u; } v; v.f = f;
    unsigned r = v.u + 0x7fffu + ((v.u >> 16) & 1u);   // round-to-nearest-even
    return (ushort_t)(r >> 16);
}

__device__ __forceinline__ void async_copy16(const void* g, void* l) {
    __builtin_amdgcn_global_load_lds(
        (const __attribute__((address_space(1))) void*)g,
        (__attribute__((address_space(3))) void*)l, 16, 0, 0);
}

// ---- kernel 1: x (f32) -> A (bf16), 8 elems/thread ----
__global__ __launch_bounds__(256) void convert_x(const float* __restrict__ x,
                                                 ushort_t* __restrict__ A) {
    int t = blockIdx.x * 256 + threadIdx.x;
    const float4* p = (const float4*)x + (size_t)t * 2;
    float4 a = p[0], b = p[1];
    short8 o;
    o[0] = (short)f2bf(a.x); o[1] = (short)f2bf(a.y);
    o[2] = (short)f2bf(a.z); o[3] = (short)f2bf(a.w);
    o[4] = (short)f2bf(b.x); o[5] = (short)f2bf(b.y);
    o[6] = (short)f2bf(b.z); o[7] = (short)f2bf(b.w);
    *(short8*)(A + (size_t)t * 8) = o;
}

// ---- kernel 2: codebook gather -> Bt (bf16, N x K layout) ----
// W[i][c] = codebook[indices[i*1024 + c/8]][c%8];  Bt[c][i] = W[i][c]
// NOTE: harness delivers integer inputs as int32 (NOT int64 from the reference).
__global__ __launch_bounds__(256) void dequant_wt(const int* __restrict__ indices,
                                                  const float* __restrict__ codebook,
                                                  ushort_t* __restrict__ Bt) {
    int g = blockIdx.x;                       // column group, 0..1023 (c = g*8+j)
    int i = blockIdx.y * 256 + threadIdx.x;   // K row, 0..2047
    int idx = indices[(size_t)i * 1024 + g];
    const float4* cb = (const float4*)(codebook + (size_t)idx * 8);
    float4 lo = cb[0], hi = cb[1];
    size_t base = (size_t)g * 8 * K_DIM + i;
    Bt[base + 0 * K_DIM] = f2bf(lo.x);
    Bt[base + 1 * K_DIM] = f2bf(lo.y);
    Bt[base + 2 * K_DIM] = f2bf(lo.z);
    Bt[base + 3 * K_DIM] = f2bf(lo.w);
    Bt[base + 4 * K_DIM] = f2bf(hi.x);
    Bt[base + 5 * K_DIM] = f2bf(hi.y);
    Bt[base + 6 * K_DIM] = f2bf(hi.z);
    Bt[base + 7 * K_DIM] = f2bf(hi.w);
}

// ---- kernel 3: C = A(MxK) * Bt(NxK)^T + bias, bf16 MFMA, f32 out ----
__global__ __launch_bounds__(256) void gemm_bt_bias(const ushort_t* __restrict__ A,
                                                    const ushort_t* __restrict__ Bt,
                                                    const float* __restrict__ bias,
                                                    float* __restrict__ C) {
    __shared__ __align__(16) ushort_t lds_a[BM * BK];
    __shared__ __align__(16) ushort_t lds_b[BN * BK];

    // XCD-aware swizzle: nwg=4096, divisible by 8
    int bid = blockIdx.x;
    int swz = (bid & 7) * 512 + (bid >> 3);
    int tm = swz >> 6;          // / (N/BN)=64
    int tn = swz & 63;
    int m0 = tm * BM, n0 = tn * BN;

    int tid = threadIdx.x;
    int lane = tid & 63;
    int wid = tid >> 6;
    int wm = wid >> 1, wn = wid & 1;   // 2x2 waves, each 64x64 output

    f32x4 acc[4][4];
#pragma unroll
    for (int i = 0; i < 4; i++)
#pragma unroll
        for (int j = 0; j < 4; j++) acc[i][j] = (f32x4){0.f, 0.f, 0.f, 0.f};

    for (int k0 = 0; k0 < K_DIM; k0 += BK) {
        __syncthreads();   // previous compute done before overwriting LDS
#pragma unroll
        for (int s = 0; s < 4; s++) {
            int flat = s * 256 + tid;         // 0..1023
            int row = flat >> 3;              // 8 x 16B chunks per 128B row
            int cc = flat & 7;
            const ushort_t* ga = A + (size_t)(m0 + row) * K_DIM + k0 + cc * 8;
            async_copy16(ga, (char*)lds_a + (size_t)flat * 16);
            const ushort_t* gb = Bt + (size_t)(n0 + row) * K_DIM + k0 + cc * 8;
            async_copy16(gb, (char*)lds_b + (size_t)flat * 16);
        }
        __syncthreads();   // staged (compiler drains vmcnt before barrier)

#pragma unroll
        for (int kk = 0; kk < 2; kk++) {
            short8 af[4], bf[4];
            int kbase = kk * 32 + (lane >> 4) * 8;
#pragma unroll
            for (int i = 0; i < 4; i++)
                af[i] = *(const short8*)&lds_a[(wm * 64 + i * 16 + (lane & 15)) * BK + kbase];
#pragma unroll
            for (int j = 0; j < 4; j++)
                bf[j] = *(const short8*)&lds_b[(wn * 64 + j * 16 + (lane & 15)) * BK + kbase];
#pragma unroll
            for (int i = 0; i < 4; i++)
#pragma unroll
                for (int j = 0; j < 4; j++)
                    acc[i][j] = __builtin_amdgcn_mfma_f32_16x16x32_bf16(af[i], bf[j], acc[i][j], 0, 0, 0);
        }
    }

    // epilogue: C/D layout col=lane&15, row=(lane>>4)*4+reg  [m89 verified]
    int crow = m0 + wm * 64 + ((lane >> 4) * 4);
    int ccol0 = n0 + wn * 64 + (lane & 15);
#pragma unroll
    for (int j = 0; j < 4; j++) {
        int col = ccol0 + j * 16;
        float bv = bias[col];
#pragma unroll
        for (int i = 0; i < 4; i++) {
            f32x4 v = acc[i][j];
            int r = crow + i * 16;
#pragma unroll
            for (int q = 0; q < 4; q++)
                C[(size_t)(r + q) * N_DIM + col] = v[q] + bv;
        }
    }
}

extern "C" void kernel_launch(void* const* d_in, const int* in_sizes, int n_in,
                              void* d_out, int out_size, void* d_ws, size_t ws_size,
                              hipStream_t stream) {
    const float* x = (const float*)d_in[0];
    const float* codebook = (const float*)d_in[1];
    const int* indices = (const int*)d_in[2];      // harness: integer -> int32
    const float* bias = (const float*)d_in[3];
    float* out = (float*)d_out;

    ushort_t* A  = (ushort_t*)d_ws;                               // 32 MB
    ushort_t* Bt = (ushort_t*)d_ws + (size_t)M_DIM * K_DIM;       // 32 MB

    convert_x<<<dim3(M_DIM * K_DIM / (256 * 8)), 256, 0, stream>>>(x, A);
    dequant_wt<<<dim3(1024, 8), 256, 0, stream>>>(indices, codebook, Bt);
    gemm_bt_bias<<<dim3((M_DIM / BM) * (N_DIM / BN)), 256, 0, stream>>>(A, Bt, bias, out);
}

// Round 3
// 338.712 us; speedup vs baseline: 1.2937x; 1.2937x over previous
//
#include <hip/hip_runtime.h>
#include <hip/hip_bf16.h>

typedef unsigned short ushort_t;
typedef __attribute__((ext_vector_type(8))) short short8;
typedef __attribute__((ext_vector_type(4))) float f32x4;

#define M_DIM 8192
#define N_DIM 8192
#define K_DIM 2048
#define BM 256
#define BN 256
#define BK 64
#define NT (K_DIM / BK)   // 32 K-tiles

__device__ __forceinline__ ushort_t f2bf(float f) {
    union { float f; unsigned u; } v; v.f = f;
    unsigned r = v.u + 0x7fffu + ((v.u >> 16) & 1u);   // RNE
    return (ushort_t)(r >> 16);
}

__device__ __forceinline__ void async_copy16(const void* g, void* l) {
    __builtin_amdgcn_global_load_lds(
        (const __attribute__((address_space(1))) void*)g,
        (__attribute__((address_space(3))) void*)l, 16, 0, 0);
}

#define BAR() __builtin_amdgcn_s_barrier()
#define LGKM0() do { asm volatile("s_waitcnt lgkmcnt(0)" ::: "memory"); \
                     __builtin_amdgcn_sched_barrier(0); } while (0)

// ---- kernel 1: x (f32) -> A (bf16) ----
__global__ __launch_bounds__(256) void convert_x(const float* __restrict__ x,
                                                 ushort_t* __restrict__ A) {
    int t = blockIdx.x * 256 + threadIdx.x;
    const float4* p = (const float4*)x + (size_t)t * 2;
    float4 a = p[0], b = p[1];
    short8 o;
    o[0] = (short)f2bf(a.x); o[1] = (short)f2bf(a.y);
    o[2] = (short)f2bf(a.z); o[3] = (short)f2bf(a.w);
    o[4] = (short)f2bf(b.x); o[5] = (short)f2bf(b.y);
    o[6] = (short)f2bf(b.z); o[7] = (short)f2bf(b.w);
    *(short8*)(A + (size_t)t * 8) = o;
}

// ---- kernel 2: codebook gather -> Bt (bf16, N x K layout) ----
__global__ __launch_bounds__(256) void dequant_wt(const int* __restrict__ indices,
                                                  const float* __restrict__ codebook,
                                                  ushort_t* __restrict__ Bt) {
    int g = blockIdx.x;                       // column group 0..1023
    int i = blockIdx.y * 256 + threadIdx.x;   // K row 0..2047
    int idx = indices[(size_t)i * 1024 + g];
    const float4* cb = (const float4*)(codebook + (size_t)idx * 8);
    float4 lo = cb[0], hi = cb[1];
    size_t base = (size_t)g * 8 * K_DIM + i;
    Bt[base + 0 * K_DIM] = f2bf(lo.x);
    Bt[base + 1 * K_DIM] = f2bf(lo.y);
    Bt[base + 2 * K_DIM] = f2bf(lo.z);
    Bt[base + 3 * K_DIM] = f2bf(lo.w);
    Bt[base + 4 * K_DIM] = f2bf(hi.x);
    Bt[base + 5 * K_DIM] = f2bf(hi.y);
    Bt[base + 6 * K_DIM] = f2bf(hi.z);
    Bt[base + 7 * K_DIM] = f2bf(hi.w);
}

// ---- 8-phase 256x256 GEMM helpers ----
__device__ __forceinline__ void load_af4(const ushort_t* p, const int (&off)[4][2],
                                         short8 (&fr)[4][2]) {
#pragma unroll
    for (int i = 0; i < 4; ++i)
#pragma unroll
        for (int kk = 0; kk < 2; ++kk)
            fr[i][kk] = *(const short8*)((const char*)p + off[i][kk]);
}

__device__ __forceinline__ void load_bf2(const ushort_t* p, const int (&off)[2][2],
                                         short8 (&fr)[2][2]) {
#pragma unroll
    for (int j = 0; j < 2; ++j)
#pragma unroll
        for (int kk = 0; kk < 2; ++kk)
            fr[j][kk] = *(const short8*)((const char*)p + off[j][kk]);
}

__device__ __forceinline__ void mfma16(const short8 (&af)[4][2], const short8 (&bf)[2][2],
                                       f32x4 (&acc)[8][4], int I0, int J0) {
    __builtin_amdgcn_s_setprio(1);
#pragma unroll
    for (int kk = 0; kk < 2; ++kk)
#pragma unroll
        for (int i = 0; i < 4; ++i)
#pragma unroll
            for (int j = 0; j < 2; ++j)
                acc[I0 + i][J0 + j] = __builtin_amdgcn_mfma_f32_16x16x32_bf16(
                    af[i][kk], bf[j][kk], acc[I0 + i][J0 + j], 0, 0, 0);
    __builtin_amdgcn_s_setprio(0);
}

// ---- kernel 3: C = A(MxK) * Bt(NxK)^T + bias ; 256^2 tile, 8-phase schedule ----
__global__ __launch_bounds__(512, 2) void gemm_256_8phase(const ushort_t* __restrict__ A,
                                                          const ushort_t* __restrict__ Bt,
                                                          const float* __restrict__ bias,
                                                          float* __restrict__ C) {
    // [dbuf][half][128 rows][64 bf16] per operand = 32 KiB * 2 * 2 = 128 KiB total
    __shared__ __align__(16) ushort_t lds_a[2][2][128 * 64];
    __shared__ __align__(16) ushort_t lds_b[2][2][128 * 64];

    const int bid = blockIdx.x;                      // 1024 blocks (32x32)
    const int swz = (bid & 7) * 128 + (bid >> 3);    // XCD swizzle (1024 % 8 == 0)
    const int m0 = (swz >> 5) * BM;
    const int n0 = (swz & 31) * BN;

    const int tid = threadIdx.x;
    const int lane = tid & 63;
    const int wid = tid >> 6;              // 0..7
    const int wm = wid >> 2, wn = wid & 3; // 2 x 4 wave grid
    const int lane15 = lane & 15, laneq = lane >> 4;

    // --- staging addresses: linear LDS dest granule G -> inverse-swizzled global col ---
    const int G0 = tid, G1 = 512 + tid;
    const int r0 = G0 >> 3, r1 = G1 >> 3;                 // half-tile row 0..127
    const int c0 = (G0 & 7) ^ (r0 & 7), c1 = (G1 & 7) ^ (r1 & 7);
    const size_t aoff0 = (size_t)(m0 + r0) * K_DIM + c0 * 8;
    const size_t aoff1 = (size_t)(m0 + r1) * K_DIM + c1 * 8;
    const size_t boff0 = (size_t)(n0 + r0) * K_DIM + c0 * 8;
    const size_t boff1 = (size_t)(n0 + r1) * K_DIM + c1 * 8;
    const int dq0 = G0 * 16, dq1 = G1 * 16;               // LDS byte offset in half
    const size_t HOFF = (size_t)128 * K_DIM;              // global row offset of half 1

#define STAGE_A(gt, hh) do { \
        char* _d = (char*)&lds_a[(gt) & 1][hh][0]; \
        async_copy16(A + aoff0 + (size_t)(hh) * HOFF + (size_t)(gt) * BK, _d + dq0); \
        async_copy16(A + aoff1 + (size_t)(hh) * HOFF + (size_t)(gt) * BK, _d + dq1); \
    } while (0)
#define STAGE_B(gt, hh) do { \
        char* _d = (char*)&lds_b[(gt) & 1][hh][0]; \
        async_copy16(Bt + boff0 + (size_t)(hh) * HOFF + (size_t)(gt) * BK, _d + dq0); \
        async_copy16(Bt + boff1 + (size_t)(hh) * HOFF + (size_t)(gt) * BK, _d + dq1); \
    } while (0)

    // --- swizzled ds_read byte offsets (within a [128][64] half) ---
    int offA[4][2], offB[2][2];
#pragma unroll
    for (int i = 0; i < 4; ++i) {
        int row = wm * 64 + i * 16 + lane15;
#pragma unroll
        for (int kk = 0; kk < 2; ++kk)
            offA[i][kk] = row * 128 + (((kk * 4 + laneq) ^ (row & 7)) * 16);
    }
#pragma unroll
    for (int j = 0; j < 2; ++j) {
        int row = wn * 32 + j * 16 + lane15;
#pragma unroll
        for (int kk = 0; kk < 2; ++kk)
            offB[j][kk] = row * 128 + (((kk * 4 + laneq) ^ (row & 7)) * 16);
    }

    f32x4 acc[8][4];
#pragma unroll
    for (int i = 0; i < 8; ++i)
#pragma unroll
        for (int j = 0; j < 4; ++j) acc[i][j] = (f32x4){0.f, 0.f, 0.f, 0.f};

    // --- prologue: tile0 fully + {Bh0,Ah1,Bh1} of tile1 (7 half-tiles, 14 loads) ---
    STAGE_A(0, 0); STAGE_B(0, 0); STAGE_A(0, 1); STAGE_B(0, 1);
    STAGE_B(1, 0); STAGE_A(1, 1); STAGE_B(1, 1);
    asm volatile("s_waitcnt vmcnt(6)" ::: "memory");   // tile0 landed, 3 halves in flight
    BAR();

    short8 af[4][2], bf[2][2];

    for (int g = 0; g < NT; ++g) {
        const int d = g & 1;
        // P1: (m-half 0, n-half 0) — 12 ds_reads; stage Ah0(g+1)
        load_af4(&lds_a[d][0][0], offA, af);
        load_bf2(&lds_b[d][0][0], offB, bf);
        if (g + 1 < NT) STAGE_A(g + 1, 0);
        asm volatile("s_waitcnt lgkmcnt(8)" ::: "memory");
        BAR(); LGKM0();
        mfma16(af, bf, acc, 0, 0);
        BAR();
        // P2: (m-half 1, n-half 0) — reuse bf; stage Bh0(g+2) into freed slot
        load_af4(&lds_a[d][1][0], offA, af);
        if (g + 2 < NT) STAGE_B(g + 2, 0);
        BAR(); LGKM0();
        mfma16(af, bf, acc, 4, 0);
        BAR();
        // P3: (m-half 1, n-half 1) — reuse af; stage Ah1(g+2)
        load_bf2(&lds_b[d][1][0], offB, bf);
        if (g + 2 < NT) STAGE_A(g + 2, 1);
        BAR(); LGKM0();
        mfma16(af, bf, acc, 4, 2);
        BAR();
        // P4: (m-half 0, n-half 1) — reuse bf; stage Bh1(g+2); counted vmcnt
        load_af4(&lds_a[d][0][0], offA, af);
        if (g + 2 < NT) STAGE_B(g + 2, 1);
        BAR(); LGKM0();
        mfma16(af, bf, acc, 0, 2);
        if (g < NT - 2)       { asm volatile("s_waitcnt vmcnt(6)" ::: "memory"); }
        else if (g == NT - 2) { asm volatile("s_waitcnt vmcnt(0)" ::: "memory"); }
        BAR();
    }

    // --- epilogue: bias + f32 store ---
#pragma unroll
    for (int ig = 0; ig < 8; ++ig) {
        int row = m0 + (ig >> 2) * 128 + wm * 64 + (ig & 3) * 16 + laneq * 4;
#pragma unroll
        for (int jg = 0; jg < 4; ++jg) {
            int col = n0 + (jg >> 1) * 128 + wn * 32 + (jg & 1) * 16 + lane15;
            float bv = bias[col];
            f32x4 v = acc[ig][jg];
#pragma unroll
            for (int q = 0; q < 4; ++q)
                C[(size_t)(row + q) * N_DIM + col] = v[q] + bv;
        }
    }
#undef STAGE_A
#undef STAGE_B
}

extern "C" void kernel_launch(void* const* d_in, const int* in_sizes, int n_in,
                              void* d_out, int out_size, void* d_ws, size_t ws_size,
                              hipStream_t stream) {
    const float* x = (const float*)d_in[0];
    const float* codebook = (const float*)d_in[1];
    const int* indices = (const int*)d_in[2];      // harness: integer -> int32
    const float* bias = (const float*)d_in[3];
    float* out = (float*)d_out;

    ushort_t* A  = (ushort_t*)d_ws;                               // 32 MB
    ushort_t* Bt = (ushort_t*)d_ws + (size_t)M_DIM * K_DIM;       // 32 MB

    convert_x<<<dim3(M_DIM * K_DIM / (256 * 8)), 256, 0, stream>>>(x, A);
    dequant_wt<<<dim3(1024, 8), 256, 0, stream>>>(indices, codebook, Bt);
    gemm_256_8phase<<<dim3((M_DIM / BM) * (N_DIM / BN)), 512, 0, stream>>>(A, Bt, bias, out);
}